// Round 2
// baseline (115.822 us; speedup 1.0000x reference)
//
#include <hip/hip_runtime.h>

// EmbeddingWithDropout: out[b,s,:] = weight[x[b,s],:] * ((u[x[b,s]] >= 0.1) ? 1/0.9 : 0)
// x: [64,2048] int32, weight: [100000,128] fp32, u: [100000] fp32
// out: [64,2048,128] fp32
//
// Latency-bound random gather (measured 1.1 TB/s at 1 token/thread vs 6.3 TB/s
// streaming ceiling). Fix: 8 independent gather chains per thread, phase-split
// so all x-loads issue before any dependent u/weight load, and all dependent
// loads issue before any use. Non-temporal stores keep the 67 MB output stream
// from thrashing L2/L3 copies of the weight table.
//
// Note: __builtin_nontemporal_store needs a clang ext_vector type, not HIP's
// float4 struct.

#define DIM 128
#define VEC_PER_ROW (DIM / 4)   // 32 float4 per row
#define UNROLL 8
#define BLOCK 256

typedef float f4 __attribute__((ext_vector_type(4)));

__global__ __launch_bounds__(BLOCK) void embed_dropout_kernel(
    const int* __restrict__ x,
    const float* __restrict__ weight,
    const float* __restrict__ u,
    f4* __restrict__ out,
    int n_tokens,
    int n_vec4)
{
    const int base = blockIdx.x * (BLOCK * UNROLL) + threadIdx.x;
    const f4* __restrict__ w4 = reinterpret_cast<const f4*>(weight);

    int  idx[UNROLL];
    float uval[UNROLL];
    f4   v[UNROLL];

    // Phase 1: issue all token-index loads (8 independent chains start here).
    #pragma unroll
    for (int k = 0; k < UNROLL; ++k) {
        int g = base + k * BLOCK;
        int token = g >> 5;                       // 32 float4 per row
        if (token >= n_tokens) token = n_tokens - 1;   // safe clamp, store is guarded
        idx[k] = x[token];
    }

    // Phase 2: issue all dependent loads (u + weight row slice), no consumer yet.
    #pragma unroll
    for (int k = 0; k < UNROLL; ++k) {
        int g = base + k * BLOCK;
        int off = g & 31;
        uval[k] = u[idx[k]];
        v[k] = w4[(size_t)idx[k] * VEC_PER_ROW + off];
    }

    // Phase 3: scale + streaming store.
    #pragma unroll
    for (int k = 0; k < UNROLL; ++k) {
        int g = base + k * BLOCK;
        if (g >= n_vec4) continue;
        float keep = (uval[k] >= 0.1f) ? (1.0f / 0.9f) : 0.0f;
        f4 r = v[k] * keep;
        __builtin_nontemporal_store(r, &out[g]);
    }
}

extern "C" void kernel_launch(void* const* d_in, const int* in_sizes, int n_in,
                              void* d_out, int out_size, void* d_ws, size_t ws_size,
                              hipStream_t stream) {
    const int*   x      = (const int*)d_in[0];     // [64*2048]
    const float* weight = (const float*)d_in[1];   // [100000*128]
    const float* u      = (const float*)d_in[2];   // [100000]
    f4*          out    = (f4*)d_out;

    int n_tokens = in_sizes[0];                    // 131072
    int n_vec4   = n_tokens * VEC_PER_ROW;         // 4194304 float4 elements
    int per_block = BLOCK * UNROLL;                // 2048 float4 per block
    int grid  = (n_vec4 + per_block - 1) / per_block;   // 2048 blocks

    embed_dropout_kernel<<<grid, BLOCK, 0, stream>>>(x, weight, u, out, n_tokens, n_vec4);
}